// Round 4
// baseline (877.027 us; speedup 1.0000x reference)
//
#include <hip/hip_runtime.h>

#define N_ 512
#define NPOS (N_*N_)   // 262144
#define CD 128         // C == CZ == 128
#define PADX 136       // LDS row stride (ushorts or floats): 16B-aligned, conflict-free quads

typedef unsigned short ushort_t;
typedef unsigned int   uint_t;
typedef __bf16 bf16_t;
typedef bf16_t  bf16x8 __attribute__((ext_vector_type(8)));
typedef float   f32x4  __attribute__((ext_vector_type(4)));
typedef unsigned short u16x4 __attribute__((ext_vector_type(4)));
typedef uint_t  u32x4 __attribute__((ext_vector_type(4)));

__device__ __forceinline__ float bf2f(ushort_t h) {
  union { uint_t u; float f; } v; v.u = ((uint_t)h) << 16; return v.f;
}
__device__ __forceinline__ ushort_t f2bf(float f) {
  union { float f; uint_t u; } v; v.f = f;
  uint_t u = v.u;
  return (ushort_t)((u + 0x7FFFu + ((u >> 16) & 1u)) >> 16);
}
__device__ __forceinline__ float sigm(float x) { return 1.0f / (1.0f + __expf(-x)); }

// ---- weight prep: wT[m][n][k] = gamma1[k]*W_m[k][n] (m<5) or wout^T (m=5);
// ---- gw[m][n] = sum_k gamma1[k]*W[k][n], bw[m][n] = sum_k beta1[k]*W[k][n]
__global__ void k_tw(const float* wga, const float* wa, const float* wgb, const float* wb,
                     const float* wg, const float* wout, const float* gamma1,
                     const float* beta1, ushort_t* wT, float* gw, float* bw) {
  int m = blockIdx.x;
  const float* S;
  switch (m) {
    case 0: S = wga; break; case 1: S = wa; break; case 2: S = wgb; break;
    case 3: S = wb; break; case 4: S = wg; break; default: S = wout; break;
  }
  ushort_t* d = wT + m * CD * CD;
  int n = threadIdx.x;   // 128 threads
  if (m < 5) {
    float ga = 0.f, ba = 0.f;
    for (int k = 0; k < CD; ++k) {
      float w = S[k * CD + n], gk = gamma1[k];
      ga += gk * w; ba += beta1[k] * w;
      d[n * CD + k] = f2bf(gk * w);
    }
    gw[m * CD + n] = ga; bw[m * CD + n] = ba;
  } else {
    for (int k = 0; k < CD; ++k) d[n * CD + k] = f2bf(S[k * CD + n]);
  }
}

// ---- fused LN1 + 5 projections. One block per 128-pos tile.
// aT/bT: bf16 [cout][pos]; g: f32 [pos][cz] (in d_out, overwritten later by k_out)
__global__ void k_fused(const float* __restrict__ pair, const ushort_t* __restrict__ wT,
                        const float* __restrict__ gw, const float* __restrict__ bw,
                        ushort_t* __restrict__ aT, ushort_t* __restrict__ bT,
                        float* __restrict__ gout) {
  __shared__ ushort_t xl[128][PADX];   // bf16 x tile  34.8 KB
  __shared__ ushort_t ot[128][PADX];   // output staging (bf16) / f32 [64][PADX] for g halves
  __shared__ float smu[128], srs[128];
  const int tid = threadIdx.x;
  const int lane = tid & 63, wid = tid >> 6;
  const int qd = lane >> 4, l15 = lane & 15;
  const int lane32 = lane & 31, halfw = lane >> 5;
  const int wm = wid & 1, wn = wid >> 1;
  const int pos0 = blockIdx.x * 128;

  { // load pair tile (f32, coalesced 512B/row), per-pos LN stats, bf16 into LDS
    const float* pt = pair + (size_t)pos0 * CD;
    #pragma unroll
    for (int it = 0; it < 16; ++it) {
      int row = it * 8 + wid * 2 + halfw;
      float4 v = *(const float4*)&pt[(size_t)row * CD + lane32 * 4];
      float s = v.x + v.y + v.z + v.w;
      float q = v.x * v.x + v.y * v.y + v.z * v.z + v.w * v.w;
      #pragma unroll
      for (int o = 16; o > 0; o >>= 1) { s += __shfl_xor(s, o, 64); q += __shfl_xor(q, o, 64); }
      if (lane32 == 0) {
        float m = s * (1.0f / 128.0f);
        smu[row] = m;
        srs[row] = rsqrtf(q * (1.0f / 128.0f) - m * m + 1e-5f);
      }
      u16x4 pk; pk[0] = f2bf(v.x); pk[1] = f2bf(v.y); pk[2] = f2bf(v.z); pk[3] = f2bf(v.w);
      *(u16x4*)&xl[row][lane32 * 4] = pk;
    }
  }
  __syncthreads();

  // ---- a and b: gated projections, channel-major output ----
  for (int rep = 0; rep < 2; ++rep) {
    const ushort_t* Wg = wT + (rep * 2    ) * CD * CD;
    const ushort_t* Wv = wT + (rep * 2 + 1) * CD * CD;
    const float* gwg = gw + (rep * 2) * CD; const float* bwg = bw + (rep * 2) * CD;
    const float* gwv = gw + (rep * 2 + 1) * CD; const float* bwv = bw + (rep * 2 + 1) * CD;
    f32x4 accg[4][4] = {}; f32x4 accv[4][4] = {};
    for (int kk = 0; kk < 4; ++kk) {
      bf16x8 af[4];
      #pragma unroll
      for (int i = 0; i < 4; ++i)
        af[i] = *(const bf16x8*)&xl[wm * 64 + i * 16 + l15][kk * 32 + qd * 8];
      #pragma unroll
      for (int j = 0; j < 4; ++j) {
        int crow = (wn * 64 + j * 16 + l15) * CD + kk * 32 + qd * 8;
        bf16x8 bg = *(const bf16x8*)(Wg + crow);
        bf16x8 bv = *(const bf16x8*)(Wv + crow);
        #pragma unroll
        for (int i = 0; i < 4; ++i) {
          accg[i][j] = __builtin_amdgcn_mfma_f32_16x16x32_bf16(af[i], bg, accg[i][j], 0, 0, 0);
          accv[i][j] = __builtin_amdgcn_mfma_f32_16x16x32_bf16(af[i], bv, accv[i][j], 0, 0, 0);
        }
      }
    }
    // epilogue: LN correction + sigmoid gate, stage to LDS [cout][pos]
    #pragma unroll
    for (int j = 0; j < 4; ++j) {
      int n = wn * 64 + j * 16 + l15;
      float gg = gwg[n], bg_ = bwg[n], gv = gwv[n], bv_ = bwv[n];
      #pragma unroll
      for (int i = 0; i < 4; ++i) {
        int p0 = wm * 64 + i * 16 + qd * 4;
        u16x4 pk;
        #pragma unroll
        for (int r = 0; r < 4; ++r) {
          int p = p0 + r;
          float zg = srs[p] * (accg[i][j][r] - smu[p] * gg) + bg_;
          float zv = srs[p] * (accv[i][j][r] - smu[p] * gv) + bv_;
          pk[r] = f2bf(sigm(zg) * zv);
        }
        *(u16x4*)&ot[n][p0] = pk;
      }
    }
    __syncthreads();
    ushort_t* dst = rep ? bT : aT;
    #pragma unroll
    for (int it = 0; it < 8; ++it) {   // 128 rows x 256B contiguous
      int v = tid + it * 256;
      int row = v >> 4, col = (v & 15) * 8;
      *(u32x4*)&dst[(size_t)row * NPOS + pos0 + col] = *(const u32x4*)&ot[row][col];
    }
    __syncthreads();
  }

  // ---- g = sigmoid(z @ wgate), f32 [pos][cz] ----
  {
    const ushort_t* Wg4 = wT + 4 * CD * CD;
    const float* gw4 = gw + 4 * CD; const float* bw4 = bw + 4 * CD;
    f32x4 acc[4][4] = {};
    for (int kk = 0; kk < 4; ++kk) {
      bf16x8 af[4];
      #pragma unroll
      for (int i = 0; i < 4; ++i)
        af[i] = *(const bf16x8*)&xl[wm * 64 + i * 16 + l15][kk * 32 + qd * 8];
      #pragma unroll
      for (int j = 0; j < 4; ++j) {
        bf16x8 bz = *(const bf16x8*)(Wg4 + (wn * 64 + j * 16 + l15) * CD + kk * 32 + qd * 8);
        #pragma unroll
        for (int i = 0; i < 4; ++i)
          acc[i][j] = __builtin_amdgcn_mfma_f32_16x16x32_bf16(af[i], bz, acc[i][j], 0, 0, 0);
      }
    }
    float* ot32 = (float*)ot;   // [64][PADX] f32 = same 34.8 KB buffer
    for (int h = 0; h < 2; ++h) {
      __syncthreads();
      if (wm == h) {
        #pragma unroll
        for (int j = 0; j < 4; ++j) {
          int n = wn * 64 + j * 16 + l15;
          float gn = gw4[n], bn = bw4[n];
          #pragma unroll
          for (int i = 0; i < 4; ++i)
            #pragma unroll
            for (int r = 0; r < 4; ++r) {
              int pl = i * 16 + qd * 4 + r;          // tile-local row within half
              int p = wm * 64 + pl;
              ot32[pl * PADX + n] = sigm(srs[p] * (acc[i][j][r] - smu[p] * gn) + bn);
            }
        }
      }
      __syncthreads();
      #pragma unroll
      for (int it = 0; it < 8; ++it) {  // 64 rows x 512B contiguous
        int v = tid + it * 256;
        int row = v >> 5, col = (v & 31) * 4;
        *(float4*)&gout[(size_t)(pos0 + h * 64 + row) * CD + col] = *(const float4*)&ot32[row * PADX + col];
      }
    }
  }
}

// ---- triangle einsum: per channel c, U_c = A_c · B_c^T; LDS-staged coalesced output ----
__global__ void k_tri(const ushort_t* __restrict__ aT, const ushort_t* __restrict__ bT,
                      ushort_t* __restrict__ uT) {
  __shared__ ushort_t lA[128][32];  // 8KB
  __shared__ ushort_t lB[128][32];
  __shared__ ushort_t ot[128][PADX]; // 34.8KB output staging
  const int tid = threadIdx.x;
  const int lane = tid & 63, wid = tid >> 6;
  const int qd = lane >> 4, l15 = lane & 15;
  const int wm = wid & 1, wn = wid >> 1;
  const int c  = blockIdx.z;
  const int m0 = blockIdx.y * 128, n0 = blockIdx.x * 128;
  const ushort_t* A = aT + (size_t)c * NPOS;  // [512][512]
  const ushort_t* B = bT + (size_t)c * NPOS;
  const int sr = tid >> 2, sc = (tid & 3) * 8;
  f32x4 acc[4][4] = {};
  for (int kk = 0; kk < N_; kk += 32) {
    __syncthreads();
    *(u32x4*)&lA[sr     ][sc] = *(const u32x4*)&A[(size_t)(m0 + sr)      * N_ + kk + sc];
    *(u32x4*)&lA[sr + 64][sc] = *(const u32x4*)&A[(size_t)(m0 + 64 + sr) * N_ + kk + sc];
    *(u32x4*)&lB[sr     ][sc] = *(const u32x4*)&B[(size_t)(n0 + sr)      * N_ + kk + sc];
    *(u32x4*)&lB[sr + 64][sc] = *(const u32x4*)&B[(size_t)(n0 + 64 + sr) * N_ + kk + sc];
    __syncthreads();
    bf16x8 af[4], bfr[4];
    #pragma unroll
    for (int t = 0; t < 4; ++t) af[t]  = *(const bf16x8*)&lA[wm * 64 + t * 16 + l15][qd * 8];
    #pragma unroll
    for (int t = 0; t < 4; ++t) bfr[t] = *(const bf16x8*)&lB[wn * 64 + t * 16 + l15][qd * 8];
    #pragma unroll
    for (int i = 0; i < 4; ++i)
      #pragma unroll
      for (int j = 0; j < 4; ++j)
        acc[i][j] = __builtin_amdgcn_mfma_f32_16x16x32_bf16(af[i], bfr[j], acc[i][j], 0, 0, 0);
  }
  // stage D tile to LDS (scalar writes), then coalesced 256B-row stores
  #pragma unroll
  for (int i = 0; i < 4; ++i)
    #pragma unroll
    for (int j = 0; j < 4; ++j) {
      int nc = wn * 64 + j * 16 + l15;
      #pragma unroll
      for (int r = 0; r < 4; ++r)
        ot[wm * 64 + i * 16 + qd * 4 + r][nc] = f2bf(acc[i][j][r]);
    }
  __syncthreads();
  ushort_t* U = uT + (size_t)c * NPOS;
  #pragma unroll
  for (int it = 0; it < 8; ++it) {
    int v = tid + it * 256;
    int row = v >> 4, col = (v & 15) * 8;
    *(u32x4*)&U[(size_t)(m0 + row) * N_ + n0 + col] = *(const u32x4*)&ot[row][col];
  }
}

// ---- LN2 + @w_out + gate (f32 gate in d_out, overwritten in place) ----
__global__ void k_out(const ushort_t* __restrict__ uT, const ushort_t* __restrict__ wT,
                      const float* __restrict__ g2, const float* __restrict__ b2,
                      float* __restrict__ gout) {
  __shared__ ushort_t nu[128][PADX];  // [pos][c] 34.8KB (raw then normalized)
  __shared__ float ps[2][128], pq[2][128];
  __shared__ float mu[128], rsd[128], gam[128], bet[128];
  const int tid = threadIdx.x;
  const int lane = tid & 63, wid = tid >> 6;
  const int qd = lane >> 4, l15 = lane & 15;
  const int pos0 = blockIdx.x * 128;
  const ushort_t* WoT = wT + 5 * CD * CD;   // w_outT [cz][c]

  if (tid < 128) { gam[tid] = g2[tid]; bet[tid] = b2[tid]; }

  { // pass 1: load raw U tile (transposed into nu[pos][c]) + LN2 stats
    int p = tid & 127, h = tid >> 7;
    float s = 0.f, sq = 0.f;
    for (int cc = h * 64; cc < h * 64 + 64; ++cc) {
      ushort_t raw = uT[(size_t)cc * NPOS + pos0 + p];
      nu[p][cc] = raw;
      float v = bf2f(raw); s += v; sq += v * v;
    }
    ps[h][p] = s; pq[h][p] = sq;
  }
  __syncthreads();
  if (tid < 128) {
    float s = ps[0][tid] + ps[1][tid];
    float m = s * (1.0f / 128.0f);
    float v = (pq[0][tid] + pq[1][tid]) * (1.0f / 128.0f) - m * m;
    mu[tid] = m; rsd[tid] = rsqrtf(v + 1e-5f);
  }
  __syncthreads();
  { // pass 2: normalize in place
    int p = tid & 127, h = tid >> 7;
    float m = mu[p], rs = rsd[p];
    for (int cc = h * 64; cc < h * 64 + 64; ++cc)
      nu[p][cc] = f2bf((bf2f(nu[p][cc]) - m) * rs * gam[cc] + bet[cc]);
  }
  __syncthreads();

  // GEMM: D[cz][pos] = WoT[cz][c] · nu[pos][c]^T
  const int wm = wid & 1, wn = wid >> 1;
  f32x4 acc[4][4] = {};
  for (int kk = 0; kk < 4; ++kk) {
    bf16x8 af[4];
    #pragma unroll
    for (int i = 0; i < 4; ++i)
      af[i] = *(const bf16x8*)(WoT + (wm * 64 + i * 16 + l15) * CD + kk * 32 + qd * 8);
    #pragma unroll
    for (int j = 0; j < 4; ++j) {
      bf16x8 bn = *(const bf16x8*)&nu[wn * 64 + j * 16 + l15][kk * 32 + qd * 8];
      #pragma unroll
      for (int i = 0; i < 4; ++i)
        acc[i][j] = __builtin_amdgcn_mfma_f32_16x16x32_bf16(af[i], bn, acc[i][j], 0, 0, 0);
    }
  }
  #pragma unroll
  for (int i = 0; i < 4; ++i) {
    int cz = wm * 64 + i * 16 + qd * 4;
    #pragma unroll
    for (int j = 0; j < 4; ++j) {
      int pos = pos0 + wn * 64 + j * 16 + l15;
      float4 gv = *(const float4*)&gout[(size_t)pos * CD + cz];   // read gate first
      float4 pk;
      pk.x = gv.x * acc[i][j][0]; pk.y = gv.y * acc[i][j][1];
      pk.z = gv.z * acc[i][j][2]; pk.w = gv.w * acc[i][j][3];
      *(float4*)&gout[(size_t)pos * CD + cz] = pk;                // overwrite with output
    }
  }
}

extern "C" void kernel_launch(void* const* d_in, const int* in_sizes, int n_in,
                              void* d_out, int out_size, void* d_ws, size_t ws_size,
                              hipStream_t stream) {
  const float* pair = (const float*)d_in[0];
  const float* g1   = (const float*)d_in[1];
  const float* b1   = (const float*)d_in[2];
  const float* wga  = (const float*)d_in[3];
  const float* wgb  = (const float*)d_in[4];
  const float* wa   = (const float*)d_in[5];
  const float* wb   = (const float*)d_in[6];
  const float* g2   = (const float*)d_in[7];
  const float* b2   = (const float*)d_in[8];
  const float* wout = (const float*)d_in[9];
  const float* wg   = (const float*)d_in[10];

  char* ws = (char*)d_ws;
  ushort_t* aT = (ushort_t*)(ws);                 // 64MiB bf16 [c][pos]
  ushort_t* bT = (ushort_t*)(ws + 67108864);      // 64MiB bf16 [c][pos]
  ushort_t* uT = (ushort_t*)(ws + 134217728);     // 64MiB bf16 [c][pos]
  ushort_t* wT = (ushort_t*)(ws + 201326592);     // 6*32KB bf16 prepped weights
  float*    gw = (float*)(ws + 201326592 + 196608);
  float*    bw = gw + 5 * CD;
  float*    gb = (float*)d_out;                   // f32 gate staged in d_out, then final output

  k_tw   <<<6, 128, 0, stream>>>(wga, wa, wgb, wb, wg, wout, g1, b1, wT, gw, bw);
  k_fused<<<2048, 256, 0, stream>>>(pair, wT, gw, bw, aT, bT, gb);
  k_tri  <<<dim3(4, 4, 128), 256, 0, stream>>>(aT, bT, uT);
  k_out  <<<2048, 256, 0, stream>>>(uT, wT, g2, b2, gb);
}